// Round 16
// baseline (240.688 us; speedup 1.0000x reference)
//
#include <hip/hip_runtime.h>
#include <hip/hip_fp16.h>

// GCN edge-predictor encoder, R16: R13 config + dst-range fill.
//   m = relu(A^2 x (Wb@Wmu) + (A1)(bb@Wmu) + bmu), s likewise with W_ls.
// Chain (7 dispatches):
//   mega1 [f2h(x)->xh + zero cnt/flags + Wc=Wb@W2 split-fp16 + pm/ps]
//   -> count -> scan1p (49-block decoupled lookback)
//   -> fill: 49 dst-chunks x 16 edge-slices; block streams its slice of
//      dst[] (L2/L3-resident) and emits only edges in its 1024-node chunk
//      -> col writes cluster in a ~48KB region per chunk (16 writers, not
//      2344) -> kills the 64B-line ping-pong (R13: 36MB HBM for 2.4MB col).
//      (R15's nontemporal store was WORSE: 45MB write-through partials.)
//   -> agg1: t1h = A@xh -> agg2: zh = A@t1h + r = A@1
//   -> gemm: m,s = relu(zh@Wc + r*p + b), f16 MFMA 2-pass (Wh+Wl).

#define CH 128
#define SCAN_CHUNK 1024
#define FILL_SLICES 16

typedef __attribute__((ext_vector_type(8))) _Float16 half8v;
typedef __attribute__((ext_vector_type(16))) float floatx16;

__global__ void count_kernel(const int* __restrict__ ei, int E, int* __restrict__ cnt) {
  int e = blockIdx.x * blockDim.x + threadIdx.x;
  if (e < E) atomicAdd(&cnt[ei[E + e]], 1);
}

// Single-pass device-wide scan over cnt (nb blocks of SCAN_CHUNK):
// per-block sum -> publish gsum+flag -> wait predecessors -> offset ->
// local scan -> write rowptr/cursor/dinv; last block writes rowptr[n].
__global__ __launch_bounds__(256) void scan1p_kernel(const int* __restrict__ cnt,
    int n, int nb, int* __restrict__ gsum, int* __restrict__ flags,
    int* __restrict__ rowptr, int* __restrict__ cursor, float* __restrict__ dinv) {
  __shared__ int sthr[256];
  __shared__ int soff;
  int bid = blockIdx.x;
  int base = bid * SCAN_CHUNK;
  int tid = threadIdx.x;
  int v[4];
  int ts = 0;
  #pragma unroll
  for (int j = 0; j < 4; ++j) {
    int i = base + tid * 4 + j;
    v[j] = (i < n) ? cnt[i] : 0;
    ts += v[j];
  }
  sthr[tid] = ts;
  if (tid == 0) soff = 0;
  __syncthreads();
  for (int off = 1; off < 256; off <<= 1) {   // inclusive scan of thread sums
    int t = (tid >= off) ? sthr[tid - off] : 0;
    __syncthreads();
    sthr[tid] += t;
    __syncthreads();
  }
  int blocksum = sthr[255];
  if (tid == 0) {                             // publish aggregate
    gsum[bid] = blocksum;
    __threadfence();
    atomicExch(&flags[bid], 1);
  }
  for (int j = tid; j < bid; j += 256) {      // parallel lookback
    while (atomicAdd(&flags[j], 0) == 0) {}
    atomicAdd(&soff, atomicAdd(&gsum[j], 0));
  }
  __syncthreads();
  int offset = soff;
  int excl = sthr[tid] - ts + offset;
  #pragma unroll
  for (int j = 0; j < 4; ++j) {
    int i = base + tid * 4 + j;
    if (i < n) {
      rowptr[i] = excl;
      cursor[i] = excl;
      dinv[i]   = rsqrtf((float)(v[j] + 1));
      excl += v[j];
    }
  }
  if (bid == nb - 1 && tid == 0) rowptr[n] = offset + blocksum;
}

// dst-range fill: block (chunk, slice) streams slice of dst[], emits edges
// with dst in [chunk*1024, chunk*1024+1024). Writes cluster per chunk.
__global__ __launch_bounds__(256) void fill_kernel(const int* __restrict__ ei,
    int E, int* __restrict__ cursor, int* __restrict__ col) {
  int chunk = blockIdx.x / FILL_SLICES;
  int slice = blockIdx.x % FILL_SLICES;
  int lo = chunk * SCAN_CHUNK, hi = lo + SCAN_CHUNK;
  int per = (E + FILL_SLICES - 1) / FILL_SLICES;
  int s = slice * per;
  int e_end = min(s + per, E);
  const int* dst = ei + E;
  for (int e = s + (int)threadIdx.x; e < e_end; e += 256) {
    int d = dst[e];
    if (d >= lo && d < hi) {
      int pos = atomicAdd(&cursor[d], 1);
      col[pos] = ei[e];
    }
  }
}

// mega1: blocks 0-31: Wc = Wb@W2 -> transposed split-fp16 [c][k] hi/lo.
// block 32: pm/ps + zero flags. blocks 33+: f2h(x) + zero cnt.
__global__ __launch_bounds__(256) void mega1_kernel(
    const float* __restrict__ x, ushort* __restrict__ xh, int n8,
    int* __restrict__ cnt, int ncnt4, int* __restrict__ flags,
    const float* __restrict__ Wb, const float* __restrict__ bb,
    const float* __restrict__ Wmu, const float* __restrict__ Wls,
    ushort* __restrict__ Wcmh, ushort* __restrict__ Wcml,
    ushort* __restrict__ Wcsh, ushort* __restrict__ Wcsl,
    float* __restrict__ pm, float* __restrict__ ps) {
  int gid = blockIdx.x;
  int tid = threadIdx.x;
  if (gid < 32) {
    int sel = gid >> 4;
    const float* W2 = sel ? Wls : Wmu;
    ushort* Wh = sel ? Wcsh : Wcmh;
    ushort* Wl = sel ? Wcsl : Wcml;
    int o = (gid & 15) * 1024 + tid * 4;      // [k][c] linear, 4 consecutive c
    int k = o >> 7, c = o & 127;
    float acc[4] = {0.f, 0.f, 0.f, 0.f};
    for (int j = 0; j < 128; ++j) {
      float a = Wb[k * 128 + j];
      const float* wr = &W2[j * 128 + c];
      acc[0] = fmaf(a, wr[0], acc[0]);
      acc[1] = fmaf(a, wr[1], acc[1]);
      acc[2] = fmaf(a, wr[2], acc[2]);
      acc[3] = fmaf(a, wr[3], acc[3]);
    }
    #pragma unroll
    for (int j = 0; j < 4; ++j) {             // write transposed [c][k] split fp16
      _Float16 h = (_Float16)acc[j];
      float resid = acc[j] - (float)h;
      _Float16 l = (_Float16)resid;
      Wh[(c + j) * 128 + k] = __builtin_bit_cast(ushort, h);
      Wl[(c + j) * 128 + k] = __builtin_bit_cast(ushort, l);
    }
  } else if (gid == 32) {
    if (tid < 16) ((int4*)flags)[tid] = make_int4(0, 0, 0, 0);
    int sel = tid >> 7, c = tid & 127;
    const float* W2 = sel ? Wls : Wmu;
    float acc = 0.f;
    for (int j = 0; j < 128; ++j) acc = fmaf(bb[j], W2[j * 128 + c], acc);
    (sel ? ps : pm)[c] = acc;
  } else {
    int t = (gid - 33) * 256 + tid;
    if (t < ncnt4) ((int4*)cnt)[t] = make_int4(0, 0, 0, 0);
    if (t < n8) {
      const float4* f4 = (const float4*)x;
      float4 a = f4[2 * t], b = f4[2 * t + 1];
      __half h[8] = {__float2half_rn(a.x), __float2half_rn(a.y),
                     __float2half_rn(a.z), __float2half_rn(a.w),
                     __float2half_rn(b.x), __float2half_rn(b.y),
                     __float2half_rn(b.z), __float2half_rn(b.w)};
      ((uint4*)xh)[t] = *(const uint4*)h;
    }
  }
}

__device__ inline void h8_fma(uint4 v, float s, float* a) {
  const __half2* h2 = (const __half2*)&v;
  #pragma unroll
  for (int i = 0; i < 4; ++i) {
    float2 f = __half22float2(h2[i]);
    a[2 * i]     = fmaf(s, f.x, a[2 * i]);
    a[2 * i + 1] = fmaf(s, f.y, a[2 * i + 1]);
  }
}

// One wave per node; 4 edge-groups of 16 lanes; lane cl owns channels
// cl*8..cl*8+7 (one 16B uint4 = 8 halfs per row). Accum f32, output fp16.
// out[w] = dinv[w] * ( dinv[w]*feat[w] + sum_src dinv[src]*feat[src] ).
// r_out (optional): r[w] = dinv[w]*(dinv[w] + sum_src dinv[src]) = (A@1)[w].
__global__ __launch_bounds__(256) void agg_kernel(const ushort* __restrict__ feat,
    const int* __restrict__ rowptr, const int* __restrict__ col,
    const float* __restrict__ dinv,
    ushort* __restrict__ out_h, float* __restrict__ r_out, int n) {
  int w = (blockIdx.x * 256 + threadIdx.x) >> 6;
  if (w >= n) return;
  int lane = threadIdx.x & 63;
  int g  = lane >> 4;        // edge group 0..3
  int cl = lane & 15;        // uint4 slot (8 channels)
  const uint4* u4 = (const uint4*)feat;
  float di = dinv[w];
  float a[8] = {0.f, 0.f, 0.f, 0.f, 0.f, 0.f, 0.f, 0.f};
  float rsum = 0.f;
  if (g == 0) {              // self-loop term, scaled by dinv[w]
    h8_fma(u4[(size_t)w * 16 + cl], di, a);
  }
  int s = rowptr[w], e = rowptr[w + 1];
  int j = s;
  for (; j + 16 <= e; j += 16) {   // 4 edges per group
    int c0 = col[j + g];
    int c1 = col[j + 4 + g];
    int c2 = col[j + 8 + g];
    int c3 = col[j + 12 + g];
    float s0 = dinv[c0], s1 = dinv[c1], s2 = dinv[c2], s3 = dinv[c3];
    rsum += (s0 + s1) + (s2 + s3);
    uint4 v0 = u4[(size_t)c0 * 16 + cl];
    uint4 v1 = u4[(size_t)c1 * 16 + cl];
    uint4 v2 = u4[(size_t)c2 * 16 + cl];
    uint4 v3 = u4[(size_t)c3 * 16 + cl];
    h8_fma(v0, s0, a);
    h8_fma(v1, s1, a);
    h8_fma(v2, s2, a);
    h8_fma(v3, s3, a);
  }
  for (; j + 8 <= e; j += 8) {     // 2 edges per group
    int c0 = col[j + g];
    int c1 = col[j + 4 + g];
    float s0 = dinv[c0], s1 = dinv[c1];
    rsum += s0 + s1;
    uint4 v0 = u4[(size_t)c0 * 16 + cl];
    uint4 v1 = u4[(size_t)c1 * 16 + cl];
    h8_fma(v0, s0, a);
    h8_fma(v1, s1, a);
  }
  for (; j < e; j += 4) {          // <=1 edge per group, masked
    int jj = j + g;
    if (jj < e) {
      int c = col[jj];
      float s0 = dinv[c];
      rsum += s0;
      h8_fma(u4[(size_t)c * 16 + cl], s0, a);
    }
  }
  // reduce across the 4 groups (xor 16, then 32)
  #pragma unroll
  for (int m = 16; m <= 32; m <<= 1) {
    #pragma unroll
    for (int i = 0; i < 8; ++i) a[i] += __shfl_xor(a[i], m);
    rsum += __shfl_xor(rsum, m);
  }
  if (g == 0) {
    __half h[8];
    #pragma unroll
    for (int i = 0; i < 8; ++i) h[i] = __float2half_rn(a[i] * di);
    ((uint4*)out_h)[(size_t)w * 16 + cl] = *(const uint4*)h;
    if (r_out && cl == 0) r_out[w] = di * (di + rsum);
  }
}

// MFMA GEMM, col-split: out = relu(A@W + r*p + b). A = fp16 [M][128] (regs),
// W = split-fp16 transposed [c][k], 64-col slice in 32KB swizzled LDS.
// f16 MFMA, 2 passes (A@Wh + A@Wl). Block = 4 waves x 32 rows = 128 rows x
// 64 cols. blockIdx.y = mat*2 + colhalf.
__global__ __launch_bounds__(256) void gemm_mfma_kernel(
    const ushort* __restrict__ Ah16,
    const ushort* __restrict__ W0h, const ushort* __restrict__ W0l,
    const float* __restrict__ p0, const float* __restrict__ b0,
    const ushort* __restrict__ W1h, const ushort* __restrict__ W1l,
    const float* __restrict__ p1, const float* __restrict__ b1,
    const float* __restrict__ rbuf,
    float* __restrict__ out0, float* __restrict__ out1,
    int M) {
  __shared__ ushort Wh[64 * 128];    // 16KB, swizzled 16B slots
  __shared__ ushort Wl[64 * 128];    // 16KB

  const int mat = blockIdx.y >> 1;
  const int c0  = (blockIdx.y & 1) * 64;
  const uint4* GH = (const uint4*)(mat ? W1h : W0h);
  const uint4* GL = (const uint4*)(mat ? W1l : W0l);
  const float* pp = mat ? p1 : p0;
  const float* bb = mat ? b1 : b0;
  float*     outp = mat ? out1 : out0;

  const int tid  = threadIdx.x;
  const int lane = tid & 63;
  const int wv   = tid >> 6;         // wave id 0..3
  const int rA   = lane & 31;        // A row-in-tile / W col-in-tile
  const int kh   = lane >> 5;        // k half
  const int row  = blockIdx.x * 128 + wv * 32 + rA;
  const bool rowok = row < M;

  // stage W cols [c0, c0+64), hi/lo: 1024 16B slots each
  {
    uint4* LH = (uint4*)Wh;
    uint4* LL = (uint4*)Wl;
    #pragma unroll
    for (int t = 0; t < 4; ++t) {
      int q = tid + t * 256;         // 0..1023
      int wr = q >> 4, ls = q & 15;
      int phys = ls ^ (wr & 15);
      LH[wr * 16 + phys] = GH[(c0 + wr) * 16 + ls];
      LL[wr * 16 + phys] = GL[(c0 + wr) * 16 + ls];
    }
  }

  const uint4* AH = (const uint4*)Ah16;
  const uint4 zero4 = make_uint4(0, 0, 0, 0);

  // A fragments for all 8 k-chunks (16B = 8 halfs each).
  half8v ah[8];
  #pragma unroll
  for (int kc = 0; kc < 8; ++kc) {
    uint4 v = rowok ? AH[row * 16 + kc * 2 + kh] : zero4;
    ah[kc] = __builtin_bit_cast(half8v, v);
  }

  __syncthreads();

  floatx16 acc[2];
  #pragma unroll
  for (int t = 0; t < 2; ++t)
    #pragma unroll
    for (int j = 0; j < 16; ++j) acc[t][j] = 0.f;

  const uint4* WHv = (const uint4*)Wh;
  const uint4* WLv = (const uint4*)Wl;

  #pragma unroll
  for (int kc = 0; kc < 8; ++kc) {
    int fk = kc * 2 + kh;
    int ph = fk ^ (rA & 15);         // swizzled slot (wrow&15 == rA&15)
    half8v wh[2], wl[2];
    #pragma unroll
    for (int t = 0; t < 2; ++t) {
      wh[t] = __builtin_bit_cast(half8v, WHv[(t * 32 + rA) * 16 + ph]);
      wl[t] = __builtin_bit_cast(half8v, WLv[(t * 32 + rA) * 16 + ph]);
    }
    #pragma unroll
    for (int t = 0; t < 2; ++t)
      acc[t] = __builtin_amdgcn_mfma_f32_32x32x16_f16(ah[kc], wh[t], acc[t], 0, 0, 0);
    #pragma unroll
    for (int t = 0; t < 2; ++t)
      acc[t] = __builtin_amdgcn_mfma_f32_32x32x16_f16(ah[kc], wl[t], acc[t], 0, 0, 0);
  }

  float bcol[2], pcol[2];
  #pragma unroll
  for (int t = 0; t < 2; ++t) {
    bcol[t] = bb[c0 + t * 32 + rA];
    pcol[t] = pp[c0 + t * 32 + rA];
  }
  #pragma unroll
  for (int r = 0; r < 16; ++r) {
    int r32 = (r & 3) + 8 * (r >> 2) + 4 * kh;
    int orow = blockIdx.x * 128 + wv * 32 + r32;
    if (orow < M) {
      float rb = rbuf[orow];
      #pragma unroll
      for (int t = 0; t < 2; ++t) {
        float v = acc[t][r] + fmaf(rb, pcol[t], bcol[t]);
        v = fmaxf(v, 0.f);
        outp[(size_t)orow * CH + c0 + t * 32 + rA] = v;
      }
    }
  }
}

extern "C" void kernel_launch(void* const* d_in, const int* in_sizes, int n_in,
                              void* d_out, int out_size, void* d_ws, size_t ws_size,
                              hipStream_t stream) {
  const float* x      = (const float*)d_in[0];
  const int*   ei     = (const int*)d_in[1];
  const float* W_base = (const float*)d_in[2];
  const float* b_base = (const float*)d_in[3];
  const float* W_mu   = (const float*)d_in[4];
  const float* b_mu   = (const float*)d_in[5];
  const float* W_ls   = (const float*)d_in[6];
  const float* b_ls   = (const float*)d_in[7];
  float* out = (float*)d_out;

  const int N = in_sizes[0] / CH;
  const int E = in_sizes[1] / 2;

  char* ws = (char*)d_ws;
  size_t off = 0;
  auto carve = [&](size_t bytes) -> void* {
    void* p = ws + off;
    off += (bytes + 511) & ~(size_t)511;
    return p;
  };
  int*    cnt    = (int*)carve((size_t)N * 4);
  int*    rowptr = (int*)carve((size_t)(N + 1) * 4);
  int*    cursor = (int*)carve((size_t)N * 4);
  int*    col    = (int*)carve((size_t)E * 4);
  float*  dinv   = (float*)carve((size_t)N * 4);
  float*  rbuf   = (float*)carve((size_t)N * 4);
  int*    gsum   = (int*)carve((size_t)64 * 4);
  int*    flags  = (int*)carve((size_t)64 * 4);
  float*  pm   = (float*)carve((size_t)CH * 4);
  float*  ps   = (float*)carve((size_t)CH * 4);
  ushort* Wcmh = (ushort*)carve((size_t)CH * CH * 2);
  ushort* Wcml = (ushort*)carve((size_t)CH * CH * 2);
  ushort* Wcsh = (ushort*)carve((size_t)CH * CH * 2);
  ushort* Wcsl = (ushort*)carve((size_t)CH * CH * 2);
  ushort* xh   = (ushort*)carve((size_t)N * CH * 2);  // x as fp16
  ushort* t1h  = (ushort*)carve((size_t)N * CH * 2);  // A@x as fp16
  ushort* zh   = (ushort*)carve((size_t)N * CH * 2);  // z = A^2@x as fp16

  int eb = (E + 255) / 256;
  int nb = (N + SCAN_CHUNK - 1) / SCAN_CHUNK;
  int n8 = N * CH / 8;
  int ncnt4 = (N + 3) / 4;

  // 1: f2h + zero(cnt, flags) + Wc split-fp16 + pm/ps
  mega1_kernel<<<33 + (n8 + 255) / 256, 256, 0, stream>>>(
      x, xh, n8, cnt, ncnt4, flags,
      W_base, b_base, W_mu, W_ls, Wcmh, Wcml, Wcsh, Wcsl, pm, ps);
  // 2-4: CSR build
  count_kernel<<<eb, 256, 0, stream>>>(ei, E, cnt);
  scan1p_kernel<<<nb, 256, 0, stream>>>(cnt, N, nb, gsum, flags,
                                        rowptr, cursor, dinv);
  fill_kernel<<<nb * FILL_SLICES, 256, 0, stream>>>(ei, E, cursor, col);

  int ab = (N * 64 + 255) / 256;
  int gb = (N + 127) / 128;

  // 5: t1h = A@xh
  agg_kernel<<<ab, 256, 0, stream>>>(xh, rowptr, col, dinv, t1h, nullptr, N);
  // 6: zh = A@t1h, r = A@1
  agg_kernel<<<ab, 256, 0, stream>>>(t1h, rowptr, col, dinv, zh, rbuf, N);
  // 7: m = relu(zh@Wcm + r*pm + bmu), s = relu(zh@Wcs + r*ps + bls)
  gemm_mfma_kernel<<<dim3(gb, 4), 256, 0, stream>>>(zh,
                                           Wcmh, Wcml, pm, b_mu,
                                           Wcsh, Wcsl, ps, b_ls,
                                           rbuf, out, out + (size_t)N * CH, N);
}

// Round 17
// 140.463 us; speedup vs baseline: 1.7135x; 1.7135x over previous
//
#include <hip/hip_runtime.h>
#include <hip/hip_fp16.h>

// GCN edge-predictor encoder, R17: R13 structure + seq-based atomic-free fill.
//   m = relu(A^2 x (Wb@Wmu) + (A1)(bb@Wmu) + bmu), s likewise with W_ls.
// Chain (7 dispatches):
//   mega1 [f2h(x)->xh + zero cnt/flags + Wc=Wb@W2 split-fp16 + pm/ps]
//   -> count  [seq[e] = atomicAdd(&cnt[dst],1)  -- sequence saved]
//   -> scan1p (49-block decoupled lookback; no cursor needed)
//   -> fill   [col[rowptr[dst]+seq[e]] = src  -- NO atomics]
//   -> agg1: t1h = A@xh -> agg2: zh = A@t1h + r = A@1
//   -> gemm: m,s = relu(zh@Wc + r*p + b), f16 MFMA 2-pass (Wh+Wl).
// Fill history: plain atomic 42.5us / nt-store 51us (R15, worse) /
// dst-range 112us (R16, worse). This removes the cursor atomic RMW;
// the ~36MB scattered-write line traffic is granule physics.

#define CH 128
#define SCAN_CHUNK 1024

typedef __attribute__((ext_vector_type(8))) _Float16 half8v;
typedef __attribute__((ext_vector_type(16))) float floatx16;

__global__ void count_kernel(const int* __restrict__ ei, int E,
                             int* __restrict__ cnt, int* __restrict__ seq) {
  int e = blockIdx.x * blockDim.x + threadIdx.x;
  if (e < E) seq[e] = atomicAdd(&cnt[ei[E + e]], 1);
}

// Single-pass device-wide scan over cnt (nb blocks of SCAN_CHUNK):
// per-block sum -> publish gsum+flag -> wait predecessors -> offset ->
// local scan -> write rowptr/dinv; last block writes rowptr[n].
__global__ __launch_bounds__(256) void scan1p_kernel(const int* __restrict__ cnt,
    int n, int nb, int* __restrict__ gsum, int* __restrict__ flags,
    int* __restrict__ rowptr, float* __restrict__ dinv) {
  __shared__ int sthr[256];
  __shared__ int soff;
  int bid = blockIdx.x;
  int base = bid * SCAN_CHUNK;
  int tid = threadIdx.x;
  int v[4];
  int ts = 0;
  #pragma unroll
  for (int j = 0; j < 4; ++j) {
    int i = base + tid * 4 + j;
    v[j] = (i < n) ? cnt[i] : 0;
    ts += v[j];
  }
  sthr[tid] = ts;
  if (tid == 0) soff = 0;
  __syncthreads();
  for (int off = 1; off < 256; off <<= 1) {   // inclusive scan of thread sums
    int t = (tid >= off) ? sthr[tid - off] : 0;
    __syncthreads();
    sthr[tid] += t;
    __syncthreads();
  }
  int blocksum = sthr[255];
  if (tid == 0) {                             // publish aggregate
    gsum[bid] = blocksum;
    __threadfence();
    atomicExch(&flags[bid], 1);
  }
  for (int j = tid; j < bid; j += 256) {      // parallel lookback
    while (atomicAdd(&flags[j], 0) == 0) {}
    atomicAdd(&soff, atomicAdd(&gsum[j], 0));
  }
  __syncthreads();
  int offset = soff;
  int excl = sthr[tid] - ts + offset;
  #pragma unroll
  for (int j = 0; j < 4; ++j) {
    int i = base + tid * 4 + j;
    if (i < n) {
      rowptr[i] = excl;
      dinv[i]   = rsqrtf((float)(v[j] + 1));
      excl += v[j];
    }
  }
  if (bid == nb - 1 && tid == 0) rowptr[n] = offset + blocksum;
}

// Atomic-free fill: position = rowptr[dst] + seq (computed during count).
__global__ void fill_kernel(const int* __restrict__ ei, int E,
                            const int* __restrict__ rowptr,
                            const int* __restrict__ seq, int* __restrict__ col) {
  int e = blockIdx.x * blockDim.x + threadIdx.x;
  if (e < E) {
    int d = ei[E + e];
    col[rowptr[d] + seq[e]] = ei[e];
  }
}

// mega1: blocks 0-31: Wc = Wb@W2 -> transposed split-fp16 [c][k] hi/lo.
// block 32: pm/ps + zero flags. blocks 33+: f2h(x) + zero cnt.
__global__ __launch_bounds__(256) void mega1_kernel(
    const float* __restrict__ x, ushort* __restrict__ xh, int n8,
    int* __restrict__ cnt, int ncnt4, int* __restrict__ flags,
    const float* __restrict__ Wb, const float* __restrict__ bb,
    const float* __restrict__ Wmu, const float* __restrict__ Wls,
    ushort* __restrict__ Wcmh, ushort* __restrict__ Wcml,
    ushort* __restrict__ Wcsh, ushort* __restrict__ Wcsl,
    float* __restrict__ pm, float* __restrict__ ps) {
  int gid = blockIdx.x;
  int tid = threadIdx.x;
  if (gid < 32) {
    int sel = gid >> 4;
    const float* W2 = sel ? Wls : Wmu;
    ushort* Wh = sel ? Wcsh : Wcmh;
    ushort* Wl = sel ? Wcsl : Wcml;
    int o = (gid & 15) * 1024 + tid * 4;      // [k][c] linear, 4 consecutive c
    int k = o >> 7, c = o & 127;
    float acc[4] = {0.f, 0.f, 0.f, 0.f};
    for (int j = 0; j < 128; ++j) {
      float a = Wb[k * 128 + j];
      const float* wr = &W2[j * 128 + c];
      acc[0] = fmaf(a, wr[0], acc[0]);
      acc[1] = fmaf(a, wr[1], acc[1]);
      acc[2] = fmaf(a, wr[2], acc[2]);
      acc[3] = fmaf(a, wr[3], acc[3]);
    }
    #pragma unroll
    for (int j = 0; j < 4; ++j) {             // write transposed [c][k] split fp16
      _Float16 h = (_Float16)acc[j];
      float resid = acc[j] - (float)h;
      _Float16 l = (_Float16)resid;
      Wh[(c + j) * 128 + k] = __builtin_bit_cast(ushort, h);
      Wl[(c + j) * 128 + k] = __builtin_bit_cast(ushort, l);
    }
  } else if (gid == 32) {
    if (tid < 16) ((int4*)flags)[tid] = make_int4(0, 0, 0, 0);
    int sel = tid >> 7, c = tid & 127;
    const float* W2 = sel ? Wls : Wmu;
    float acc = 0.f;
    for (int j = 0; j < 128; ++j) acc = fmaf(bb[j], W2[j * 128 + c], acc);
    (sel ? ps : pm)[c] = acc;
  } else {
    int t = (gid - 33) * 256 + tid;
    if (t < ncnt4) ((int4*)cnt)[t] = make_int4(0, 0, 0, 0);
    if (t < n8) {
      const float4* f4 = (const float4*)x;
      float4 a = f4[2 * t], b = f4[2 * t + 1];
      __half h[8] = {__float2half_rn(a.x), __float2half_rn(a.y),
                     __float2half_rn(a.z), __float2half_rn(a.w),
                     __float2half_rn(b.x), __float2half_rn(b.y),
                     __float2half_rn(b.z), __float2half_rn(b.w)};
      ((uint4*)xh)[t] = *(const uint4*)h;
    }
  }
}

__device__ inline void h8_fma(uint4 v, float s, float* a) {
  const __half2* h2 = (const __half2*)&v;
  #pragma unroll
  for (int i = 0; i < 4; ++i) {
    float2 f = __half22float2(h2[i]);
    a[2 * i]     = fmaf(s, f.x, a[2 * i]);
    a[2 * i + 1] = fmaf(s, f.y, a[2 * i + 1]);
  }
}

// One wave per node; 4 edge-groups of 16 lanes; lane cl owns channels
// cl*8..cl*8+7 (one 16B uint4 = 8 halfs per row). Accum f32, output fp16.
// out[w] = dinv[w] * ( dinv[w]*feat[w] + sum_src dinv[src]*feat[src] ).
// r_out (optional): r[w] = dinv[w]*(dinv[w] + sum_src dinv[src]) = (A@1)[w].
__global__ __launch_bounds__(256) void agg_kernel(const ushort* __restrict__ feat,
    const int* __restrict__ rowptr, const int* __restrict__ col,
    const float* __restrict__ dinv,
    ushort* __restrict__ out_h, float* __restrict__ r_out, int n) {
  int w = (blockIdx.x * 256 + threadIdx.x) >> 6;
  if (w >= n) return;
  int lane = threadIdx.x & 63;
  int g  = lane >> 4;        // edge group 0..3
  int cl = lane & 15;        // uint4 slot (8 channels)
  const uint4* u4 = (const uint4*)feat;
  float di = dinv[w];
  float a[8] = {0.f, 0.f, 0.f, 0.f, 0.f, 0.f, 0.f, 0.f};
  float rsum = 0.f;
  if (g == 0) {              // self-loop term, scaled by dinv[w]
    h8_fma(u4[(size_t)w * 16 + cl], di, a);
  }
  int s = rowptr[w], e = rowptr[w + 1];
  int j = s;
  for (; j + 16 <= e; j += 16) {   // 4 edges per group
    int c0 = col[j + g];
    int c1 = col[j + 4 + g];
    int c2 = col[j + 8 + g];
    int c3 = col[j + 12 + g];
    float s0 = dinv[c0], s1 = dinv[c1], s2 = dinv[c2], s3 = dinv[c3];
    rsum += (s0 + s1) + (s2 + s3);
    uint4 v0 = u4[(size_t)c0 * 16 + cl];
    uint4 v1 = u4[(size_t)c1 * 16 + cl];
    uint4 v2 = u4[(size_t)c2 * 16 + cl];
    uint4 v3 = u4[(size_t)c3 * 16 + cl];
    h8_fma(v0, s0, a);
    h8_fma(v1, s1, a);
    h8_fma(v2, s2, a);
    h8_fma(v3, s3, a);
  }
  for (; j + 8 <= e; j += 8) {     // 2 edges per group
    int c0 = col[j + g];
    int c1 = col[j + 4 + g];
    float s0 = dinv[c0], s1 = dinv[c1];
    rsum += s0 + s1;
    uint4 v0 = u4[(size_t)c0 * 16 + cl];
    uint4 v1 = u4[(size_t)c1 * 16 + cl];
    h8_fma(v0, s0, a);
    h8_fma(v1, s1, a);
  }
  for (; j < e; j += 4) {          // <=1 edge per group, masked
    int jj = j + g;
    if (jj < e) {
      int c = col[jj];
      float s0 = dinv[c];
      rsum += s0;
      h8_fma(u4[(size_t)c * 16 + cl], s0, a);
    }
  }
  // reduce across the 4 groups (xor 16, then 32)
  #pragma unroll
  for (int m = 16; m <= 32; m <<= 1) {
    #pragma unroll
    for (int i = 0; i < 8; ++i) a[i] += __shfl_xor(a[i], m);
    rsum += __shfl_xor(rsum, m);
  }
  if (g == 0) {
    __half h[8];
    #pragma unroll
    for (int i = 0; i < 8; ++i) h[i] = __float2half_rn(a[i] * di);
    ((uint4*)out_h)[(size_t)w * 16 + cl] = *(const uint4*)h;
    if (r_out && cl == 0) r_out[w] = di * (di + rsum);
  }
}

// MFMA GEMM, col-split: out = relu(A@W + r*p + b). A = fp16 [M][128] (regs),
// W = split-fp16 transposed [c][k], 64-col slice in 32KB swizzled LDS.
// f16 MFMA, 2 passes (A@Wh + A@Wl). Block = 4 waves x 32 rows = 128 rows x
// 64 cols. blockIdx.y = mat*2 + colhalf.
__global__ __launch_bounds__(256) void gemm_mfma_kernel(
    const ushort* __restrict__ Ah16,
    const ushort* __restrict__ W0h, const ushort* __restrict__ W0l,
    const float* __restrict__ p0, const float* __restrict__ b0,
    const ushort* __restrict__ W1h, const ushort* __restrict__ W1l,
    const float* __restrict__ p1, const float* __restrict__ b1,
    const float* __restrict__ rbuf,
    float* __restrict__ out0, float* __restrict__ out1,
    int M) {
  __shared__ ushort Wh[64 * 128];    // 16KB, swizzled 16B slots
  __shared__ ushort Wl[64 * 128];    // 16KB

  const int mat = blockIdx.y >> 1;
  const int c0  = (blockIdx.y & 1) * 64;
  const uint4* GH = (const uint4*)(mat ? W1h : W0h);
  const uint4* GL = (const uint4*)(mat ? W1l : W0l);
  const float* pp = mat ? p1 : p0;
  const float* bb = mat ? b1 : b0;
  float*     outp = mat ? out1 : out0;

  const int tid  = threadIdx.x;
  const int lane = tid & 63;
  const int wv   = tid >> 6;         // wave id 0..3
  const int rA   = lane & 31;        // A row-in-tile / W col-in-tile
  const int kh   = lane >> 5;        // k half
  const int row  = blockIdx.x * 128 + wv * 32 + rA;
  const bool rowok = row < M;

  // stage W cols [c0, c0+64), hi/lo: 1024 16B slots each
  {
    uint4* LH = (uint4*)Wh;
    uint4* LL = (uint4*)Wl;
    #pragma unroll
    for (int t = 0; t < 4; ++t) {
      int q = tid + t * 256;         // 0..1023
      int wr = q >> 4, ls = q & 15;
      int phys = ls ^ (wr & 15);
      LH[wr * 16 + phys] = GH[(c0 + wr) * 16 + ls];
      LL[wr * 16 + phys] = GL[(c0 + wr) * 16 + ls];
    }
  }

  const uint4* AH = (const uint4*)Ah16;
  const uint4 zero4 = make_uint4(0, 0, 0, 0);

  // A fragments for all 8 k-chunks (16B = 8 halfs each).
  half8v ah[8];
  #pragma unroll
  for (int kc = 0; kc < 8; ++kc) {
    uint4 v = rowok ? AH[row * 16 + kc * 2 + kh] : zero4;
    ah[kc] = __builtin_bit_cast(half8v, v);
  }

  __syncthreads();

  floatx16 acc[2];
  #pragma unroll
  for (int t = 0; t < 2; ++t)
    #pragma unroll
    for (int j = 0; j < 16; ++j) acc[t][j] = 0.f;

  const uint4* WHv = (const uint4*)Wh;
  const uint4* WLv = (const uint4*)Wl;

  #pragma unroll
  for (int kc = 0; kc < 8; ++kc) {
    int fk = kc * 2 + kh;
    int ph = fk ^ (rA & 15);         // swizzled slot (wrow&15 == rA&15)
    half8v wh[2], wl[2];
    #pragma unroll
    for (int t = 0; t < 2; ++t) {
      wh[t] = __builtin_bit_cast(half8v, WHv[(t * 32 + rA) * 16 + ph]);
      wl[t] = __builtin_bit_cast(half8v, WLv[(t * 32 + rA) * 16 + ph]);
    }
    #pragma unroll
    for (int t = 0; t < 2; ++t)
      acc[t] = __builtin_amdgcn_mfma_f32_32x32x16_f16(ah[kc], wh[t], acc[t], 0, 0, 0);
    #pragma unroll
    for (int t = 0; t < 2; ++t)
      acc[t] = __builtin_amdgcn_mfma_f32_32x32x16_f16(ah[kc], wl[t], acc[t], 0, 0, 0);
  }

  float bcol[2], pcol[2];
  #pragma unroll
  for (int t = 0; t < 2; ++t) {
    bcol[t] = bb[c0 + t * 32 + rA];
    pcol[t] = pp[c0 + t * 32 + rA];
  }
  #pragma unroll
  for (int r = 0; r < 16; ++r) {
    int r32 = (r & 3) + 8 * (r >> 2) + 4 * kh;
    int orow = blockIdx.x * 128 + wv * 32 + r32;
    if (orow < M) {
      float rb = rbuf[orow];
      #pragma unroll
      for (int t = 0; t < 2; ++t) {
        float v = acc[t][r] + fmaf(rb, pcol[t], bcol[t]);
        v = fmaxf(v, 0.f);
        outp[(size_t)orow * CH + c0 + t * 32 + rA] = v;
      }
    }
  }
}

extern "C" void kernel_launch(void* const* d_in, const int* in_sizes, int n_in,
                              void* d_out, int out_size, void* d_ws, size_t ws_size,
                              hipStream_t stream) {
  const float* x      = (const float*)d_in[0];
  const int*   ei     = (const int*)d_in[1];
  const float* W_base = (const float*)d_in[2];
  const float* b_base = (const float*)d_in[3];
  const float* W_mu   = (const float*)d_in[4];
  const float* b_mu   = (const float*)d_in[5];
  const float* W_ls   = (const float*)d_in[6];
  const float* b_ls   = (const float*)d_in[7];
  float* out = (float*)d_out;

  const int N = in_sizes[0] / CH;
  const int E = in_sizes[1] / 2;

  char* ws = (char*)d_ws;
  size_t off = 0;
  auto carve = [&](size_t bytes) -> void* {
    void* p = ws + off;
    off += (bytes + 511) & ~(size_t)511;
    return p;
  };
  int*    cnt    = (int*)carve((size_t)N * 4);
  int*    rowptr = (int*)carve((size_t)(N + 1) * 4);
  int*    seq    = (int*)carve((size_t)E * 4);
  int*    col    = (int*)carve((size_t)E * 4);
  float*  dinv   = (float*)carve((size_t)N * 4);
  float*  rbuf   = (float*)carve((size_t)N * 4);
  int*    gsum   = (int*)carve((size_t)64 * 4);
  int*    flags  = (int*)carve((size_t)64 * 4);
  float*  pm   = (float*)carve((size_t)CH * 4);
  float*  ps   = (float*)carve((size_t)CH * 4);
  ushort* Wcmh = (ushort*)carve((size_t)CH * CH * 2);
  ushort* Wcml = (ushort*)carve((size_t)CH * CH * 2);
  ushort* Wcsh = (ushort*)carve((size_t)CH * CH * 2);
  ushort* Wcsl = (ushort*)carve((size_t)CH * CH * 2);
  ushort* xh   = (ushort*)carve((size_t)N * CH * 2);  // x as fp16
  ushort* t1h  = (ushort*)carve((size_t)N * CH * 2);  // A@x as fp16
  ushort* zh   = (ushort*)carve((size_t)N * CH * 2);  // z = A^2@x as fp16

  int eb = (E + 255) / 256;
  int nb = (N + SCAN_CHUNK - 1) / SCAN_CHUNK;
  int n8 = N * CH / 8;
  int ncnt4 = (N + 3) / 4;

  // 1: f2h + zero(cnt, flags) + Wc split-fp16 + pm/ps
  mega1_kernel<<<33 + (n8 + 255) / 256, 256, 0, stream>>>(
      x, xh, n8, cnt, ncnt4, flags,
      W_base, b_base, W_mu, W_ls, Wcmh, Wcml, Wcsh, Wcsl, pm, ps);
  // 2-4: CSR build (count saves seq; fill is atomic-free)
  count_kernel<<<eb, 256, 0, stream>>>(ei, E, cnt, seq);
  scan1p_kernel<<<nb, 256, 0, stream>>>(cnt, N, nb, gsum, flags, rowptr, dinv);
  fill_kernel<<<eb, 256, 0, stream>>>(ei, E, rowptr, seq, col);

  int ab = (N * 64 + 255) / 256;
  int gb = (N + 127) / 128;

  // 5: t1h = A@xh
  agg_kernel<<<ab, 256, 0, stream>>>(xh, rowptr, col, dinv, t1h, nullptr, N);
  // 6: zh = A@t1h, r = A@1
  agg_kernel<<<ab, 256, 0, stream>>>(t1h, rowptr, col, dinv, zh, rbuf, N);
  // 7: m = relu(zh@Wcm + r*pm + bmu), s = relu(zh@Wcs + r*ps + bls)
  gemm_mfma_kernel<<<dim3(gb, 4), 256, 0, stream>>>(zh,
                                           Wcmh, Wcml, pm, b_mu,
                                           Wcsh, Wcsl, ps, b_ls,
                                           rbuf, out, out + (size_t)N * CH, N);
}